// Round 18
// baseline (200.188 us; speedup 1.0000x reference)
//
#include <hip/hip_runtime.h>
#include <math.h>

#define LSEQ 4096
#define DDIM 1024
#define NB 4
#define NH 16
#define DHD 64
#define NFREQ 2049
#define NFMAX 4097

typedef __bf16 bf16_8 __attribute__((ext_vector_type(8)));
typedef float f32x4 __attribute__((ext_vector_type(4)));
typedef float f2 __attribute__((ext_vector_type(2)));

__device__ __forceinline__ float gelu_exact(float v) {
    return 0.5f * v * (1.0f + erff(v * 0.70710678118654752440f));
}

__device__ __forceinline__ void gload16(const void* g, void* l) {
    __builtin_amdgcn_global_load_lds((const __attribute__((address_space(1))) char*)g,
                                     (__attribute__((address_space(3))) char*)l, 16, 0, 0);
}

// ---------------- xbar partial + x -> bf16 cast (single pass over x) ----------------
__global__ __launch_bounds__(256) void k_xbar_partial(const float* __restrict__ x, float* __restrict__ xbp,
                                                      __bf16* __restrict__ xbf) {
    int d = blockIdx.x * 256 + threadIdx.x;
    int chunk = blockIdx.y;
    int b = blockIdx.z;
    size_t base = ((size_t)b * LSEQ + (size_t)chunk * 256) * DDIM + d;
    float acc = 0.f;
    for (int l = 0; l < 256; ++l) {
        float v = x[base + (size_t)l * DDIM];
        acc += v;
        xbf[base + (size_t)l * DDIM] = (__bf16)v;
    }
    xbp[(size_t)(b * 16 + chunk) * DDIM + d] = acc;
}

__global__ __launch_bounds__(256) void k_xbar_reduce(const float* __restrict__ xbp, float* __restrict__ xbar) {
    int d = blockIdx.x * 256 + threadIdx.x;
    int b = blockIdx.y;
    float acc = 0.f;
    for (int c = 0; c < 16; ++c) acc += xbp[(size_t)(b * 16 + c) * DDIM + d];
    xbar[b * DDIM + d] = acc * (1.0f / LSEQ);
}

// ---------------- weight fp32 -> bf16 ----------------
__global__ __launch_bounds__(256) void k_cvt(const float* __restrict__ s, __bf16* __restrict__ d, int n) {
    int i = (blockIdx.x * 256 + threadIdx.x) * 4;
    if (i < n) {
        float4 v = *(const float4*)(s + i);
        d[i] = (__bf16)v.x; d[i + 1] = (__bf16)v.y; d[i + 2] = (__bf16)v.z; d[i + 3] = (__bf16)v.w;
    }
}

// ---------------- q_bar = xbar @ Wq^T ----------------
__global__ __launch_bounds__(256) void k_qbar(const float* __restrict__ xbar, const float* __restrict__ Wq,
                                              float* __restrict__ qbar) {
    int lane = threadIdx.x & 63;
    int e = blockIdx.x * 4 + (threadIdx.x >> 6);
    const float* wrow = Wq + (size_t)e * DDIM;
    float a0 = 0, a1 = 0, a2 = 0, a3 = 0;
    for (int i = 0; i < 16; ++i) {
        int d = lane + i * 64;
        float w = wrow[d];
        a0 += w * xbar[d];
        a1 += w * xbar[DDIM + d];
        a2 += w * xbar[2 * DDIM + d];
        a3 += w * xbar[3 * DDIM + d];
    }
    for (int off = 32; off > 0; off >>= 1) {
        a0 += __shfl_down(a0, off);
        a1 += __shfl_down(a1, off);
        a2 += __shfl_down(a2, off);
        a3 += __shfl_down(a3, off);
    }
    if (lane == 0) {
        qbar[e] = a0;
        qbar[DDIM + e] = a1;
        qbar[2 * DDIM + e] = a2;
        qbar[3 * DDIM + e] = a3;
    }
}

// ---------------- per-(b,h) MLPs ----------------
__global__ __launch_bounds__(256) void k_mlp(const float* __restrict__ qbar,
                                             const float* __restrict__ ln_g_s, const float* __restrict__ ln_g_b,
                                             const float* __restrict__ W1, const float* __restrict__ b1,
                                             const float* __restrict__ ln_w_s, const float* __restrict__ ln_w_b,
                                             const float* __restrict__ Ww1, const float* __restrict__ bw1,
                                             const float* __restrict__ Ww2, const float* __restrict__ bw2,
                                             float* __restrict__ h1g, float* __restrict__ gwp1) {
    int bh = blockIdx.x;
    __shared__ float q[64], hg[64], hw[64], g1[64];
    __shared__ float sm, sv;
    int t = threadIdx.x;
    if (t < 64) q[t] = qbar[bh * 64 + t];
    __syncthreads();
    if (t == 0) {
        float m = 0;
        for (int i = 0; i < 64; ++i) m += q[i];
        m *= (1.0f / 64.0f);
        float v = 0;
        for (int i = 0; i < 64; ++i) { float dd = q[i] - m; v += dd * dd; }
        v *= (1.0f / 64.0f);
        sm = m; sv = v;
    }
    __syncthreads();
    if (t < 64) {
        float n = (q[t] - sm) * rsqrtf(sv + 1e-5f);
        hg[t] = n * ln_g_s[t] + ln_g_b[t];
        hw[t] = n * ln_w_s[t] + ln_w_b[t];
    }
    __syncthreads();
    {
        int f = t;
        const float* w = W1 + (size_t)f * 64;
        float s = b1[f];
        for (int d0 = 0; d0 < 64; ++d0) s += hg[d0] * w[d0];
        h1g[(size_t)bh * 256 + f] = gelu_exact(s);
    }
    if (t < 64) {
        const float* w = Ww1 + (size_t)t * 64;
        float s = bw1[t];
        for (int k = 0; k < 64; ++k) s += hw[k] * w[k];
        g1[t] = gelu_exact(s);
    }
    __syncthreads();
    if (t < 64) {
        const float* w = Ww2 + (size_t)t * 64;
        float s = bw2[t];
        for (int k = 0; k < 64; ++k) s += g1[k] * w[k];
        gwp1[bh * 64 + t] = 1.0f + 1.0f / (1.0f + expf(-s));
    }
}

// ---------------- gate rows ----------------
__global__ __launch_bounds__(256) void k_gate(const float* __restrict__ h1g, const float* __restrict__ W2,
                                              const float* __restrict__ b2,
                                              float* __restrict__ gre, float* __restrict__ gim) {
    int task = blockIdx.x * 4 + (threadIdx.x >> 6);
    if (task >= 2 * NFREQ) return;
    int lane = threadIdx.x & 63;
    int part = task >= NFREQ;
    int f = task - part * NFREQ;
    int row = part ? (NFMAX + f) : f;
    const float* w = W2 + (size_t)row * 256;
    float w0 = w[lane], w1 = w[64 + lane], w2 = w[128 + lane], w3 = w[192 + lane];
    float bias = b2[row];
    float* dst = part ? gim : gre;
    for (int bh = 0; bh < 64; ++bh) {
        const float* hr = h1g + (size_t)bh * 256;
        float p = w0 * hr[lane] + w1 * hr[64 + lane] + w2 * hr[128 + lane] + w3 * hr[192 + lane];
        for (int off = 32; off > 0; off >>= 1) p += __shfl_down(p, off);
        if (lane == 0) dst[(size_t)bh * NFREQ + f] = p + bias;
    }
}

// ================= 256x256, 8-wave, BK=64, dbuf LDS, counted-vmcnt pipeline (R12 best) =================
__device__ __forceinline__ void swz256(int bid, int& n0, int& m0, int& b) {
    int w = (bid & 7) * 32 + (bid >> 3);
    b = w >> 6;
    m0 = ((w >> 2) & 15) << 8;
    n0 = (w & 3) << 8;
}

__device__ __forceinline__ void g3_stage_half(const __bf16* __restrict__ src, int row0, int kt,
                                              char* ldshalf, int tid) {
#pragma unroll
    for (int j = 0; j < 2; ++j) {
        int c = j * 512 + tid;
        int r = c >> 3;
        int kc = ((c & 7) ^ (r & 7)) * 8;
        char* dst = ldshalf + (size_t)(j * 512 + (tid & ~63)) * 16;
        gload16(src + ((size_t)(row0 + r) << 10) + kt * 64 + kc, dst);
    }
}

__device__ __forceinline__ void g3_compute(const char* L, int db, int wm, int wn,
                                           int lrow, int lsl, f32x4 (&acc)[8][4]) {
    const char* Ab = L + db * 32768 + wm * 16384;
    const char* Bb = L + 65536 + db * 32768 + (wn >> 1) * 16384;
    int xs = lrow & 7;
    int brb = (wn & 1) * 64;
#pragma unroll
    for (int kk = 0; kk < 2; ++kk) {
        int slot = ((kk * 4 + lsl) ^ xs) << 4;
        bf16_8 af[8], bfr[4];
#pragma unroll
        for (int mi = 0; mi < 8; ++mi)
            af[mi] = *(const bf16_8*)(Ab + (mi * 16 + lrow) * 128 + slot);
#pragma unroll
        for (int ni = 0; ni < 4; ++ni)
            bfr[ni] = *(const bf16_8*)(Bb + (brb + ni * 16 + lrow) * 128 + slot);
        __builtin_amdgcn_s_setprio(1);
#pragma unroll
        for (int mi = 0; mi < 8; ++mi)
#pragma unroll
            for (int ni = 0; ni < 4; ++ni)
                acc[mi][ni] = __builtin_amdgcn_mfma_f32_16x16x32_bf16(af[mi], bfr[ni], acc[mi][ni], 0, 0, 0);
        __builtin_amdgcn_s_setprio(0);
    }
}

__device__ __forceinline__ void g3_core(const __bf16* __restrict__ A, const __bf16* __restrict__ B,
                                        int m0, int n0, char* L, f32x4 (&acc)[8][4]) {
    int tid = threadIdx.x;
    int lane = tid & 63, w = tid >> 6;
    int wm = w >> 2, wn = w & 3;
    int lrow = lane & 15, lsl = lane >> 4;
#pragma unroll
    for (int mi = 0; mi < 8; ++mi)
#pragma unroll
        for (int ni = 0; ni < 4; ++ni) acc[mi][ni] = (f32x4){0.f, 0.f, 0.f, 0.f};

#define G3_STAGE(KT, DB)                                                        \
    do {                                                                        \
        g3_stage_half(A, m0,       (KT), L + (DB) * 32768,               tid);  \
        g3_stage_half(A, m0 + 128, (KT), L + (DB) * 32768 + 16384,       tid);  \
        g3_stage_half(B, n0,       (KT), L + 65536 + (DB) * 32768,       tid);  \
        g3_stage_half(B, n0 + 128, (KT), L + 65536 + (DB) * 32768 + 16384, tid);\
    } while (0)

    G3_STAGE(0, 0);
    G3_STAGE(1, 1);
    asm volatile("s_waitcnt vmcnt(8)" ::: "memory");
    __builtin_amdgcn_s_barrier();
    asm volatile("" ::: "memory");
#pragma unroll 1
    for (int kt = 0; kt < 16; ++kt) {
        int db = kt & 1;
        g3_compute(L, db, wm, wn, lrow, lsl, acc);
        asm volatile("s_waitcnt lgkmcnt(0)" ::: "memory");
        __builtin_amdgcn_s_barrier();
        asm volatile("" ::: "memory");
        if (kt < 14) {
            G3_STAGE(kt + 2, db);
            asm volatile("s_waitcnt vmcnt(8)" ::: "memory");
            __builtin_amdgcn_s_barrier();
            asm volatile("" ::: "memory");
        } else if (kt == 14) {
            asm volatile("s_waitcnt vmcnt(0)" ::: "memory");
            __builtin_amdgcn_s_barrier();
            asm volatile("" ::: "memory");
        }
    }
#undef G3_STAGE
}

// vgemm: vt[b][e][l] (bf16) = (x @ Wv^T)^T
__global__ __launch_bounds__(512, 2) void k_vgemm(const __bf16* __restrict__ xbf, const __bf16* __restrict__ Wvb,
                                                  __bf16* __restrict__ vt) {
    __shared__ __align__(16) char L[131072 + 17408];
    __bf16 (*st)[16][68] = (__bf16(*)[16][68])(L + 131072);
    int n0, m0, b;
    swz256(blockIdx.x, n0, m0, b);
    f32x4 acc[8][4];
    g3_core(xbf + ((size_t)b << 22), Wvb, m0, n0, L, acc);
    int tid = threadIdx.x;
    int lane = tid & 63, w = tid >> 6;
    int wm = w >> 2, wn = w & 3;
    size_t vbase = ((size_t)b << 22);
#pragma unroll
    for (int ni = 0; ni < 4; ++ni) {
#pragma unroll
        for (int half = 0; half < 2; ++half) {
#pragma unroll
            for (int ml = 0; ml < 4; ++ml)
#pragma unroll
                for (int r = 0; r < 4; ++r)
                    st[w][lane & 15][ml * 16 + (lane >> 4) * 4 + r] = (__bf16)acc[half * 4 + ml][ni][r];
            asm volatile("" ::: "memory");
#pragma unroll
            for (int er = 0; er < 16; ++er) {
                vt[vbase + (size_t)(n0 + wn * 64 + ni * 16 + er) * LSEQ + m0 + wm * 128 + half * 64 + lane] =
                    st[w][er][lane];
            }
            asm volatile("" ::: "memory");
        }
    }
}

// ogemm: out[b][l][e2] (fp32) = ybf @ Wo^T
__global__ __launch_bounds__(512, 2) void k_ogemm(const __bf16* __restrict__ ybf, const __bf16* __restrict__ Wob,
                                                  float* __restrict__ out) {
    __shared__ __align__(16) char L[131072];
    int n0, m0, b;
    swz256(blockIdx.x, n0, m0, b);
    f32x4 acc[8][4];
    g3_core(ybf + ((size_t)b << 22), Wob, m0, n0, L, acc);
    int tid = threadIdx.x;
    int lane = tid & 63, w = tid >> 6;
    int wm = w >> 2, wn = w & 3;
    float* ob = out + ((size_t)b << 22);
#pragma unroll
    for (int mi = 0; mi < 8; ++mi)
#pragma unroll
        for (int ni = 0; ni < 4; ++ni)
#pragma unroll
            for (int r = 0; r < 4; ++r)
                ob[(size_t)(m0 + wm * 128 + mi * 16 + (lane >> 4) * 4 + r) * DDIM +
                   n0 + wn * 64 + ni * 16 + (lane & 15)] = acc[mi][ni][r];
}

// ================= rfft4096 per channel via cfft2048 (even/odd pack), radix 8-8-8-4 =================
// VOP3P packed complex ops; 8-byte-element-aware pad PD(i)=i+(i>>4) (bank period = 16 f2):
// verified uniform 4-lanes/bank-residue (the wave64 x 8B floor) for all strides {1x8,4,32,256}.
__device__ __forceinline__ f2 cmul2(f2 a, f2 b) {
    f2 t = a * (f2){b.x, b.x};
    f2 ayx = __builtin_shufflevector(a, a, 1, 0);
    return t + ayx * (f2){-b.y, b.y};
}
__device__ __forceinline__ f2 mulmi(f2 v) {
    f2 s = __builtin_shufflevector(v, v, 1, 0);
    return s * (f2){1.f, -1.f};
}
__device__ __forceinline__ f2 mulpi(f2 v) {
    f2 s = __builtin_shufflevector(v, v, 1, 0);
    return s * (f2){-1.f, 1.f};
}
__device__ __forceinline__ int PD(int i) { return i + (i >> 4); }
__device__ __forceinline__ int SR8(int k) {
    return ((k & 7) << 8) | (((k >> 3) & 7) << 5) | (((k >> 6) & 7) << 2) | (k >> 9);
}

#define WFENCE() asm volatile("s_waitcnt lgkmcnt(0)" ::: "memory")

template <int S>
__device__ __forceinline__ void dft4v(f2* x) {
    f2 t0 = x[0] + x[2], t1 = x[0] - x[2];
    f2 t2 = x[1] + x[3], t3 = x[1] - x[3];
    f2 j3 = (S == 1) ? mulmi(t3) : mulpi(t3);
    x[0] = t0 + t2;
    x[2] = t0 - t2;
    x[1] = t1 + j3;
    x[3] = t1 - j3;
}

template <int S>
__device__ __forceinline__ void dft8v(f2* x) {
    f2 e[4] = {x[0], x[2], x[4], x[6]};
    f2 o[4] = {x[1], x[3], x[5], x[7]};
    dft4v<S>(e);
    dft4v<S>(o);
    const float c = 0.7071067811865476f;
    const float sg = (S == 1) ? -1.f : 1.f;
    o[1] = cmul2(o[1], (f2){c, sg * c});
    o[2] = (S == 1) ? mulmi(o[2]) : mulpi(o[2]);
    o[3] = cmul2(o[3], (f2){-c, sg * c});
    x[0] = e[0] + o[0];
    x[4] = e[0] - o[0];
    x[1] = e[1] + o[1];
    x[5] = e[1] - o[1];
    x[2] = e[2] + o[2];
    x[6] = e[2] - o[2];
    x[3] = e[3] + o[3];
    x[7] = e[3] - o[3];
}

template <int S>
__device__ __forceinline__ void tw8(f2* x, int j, float invN) {
    float base = ((S == 1) ? -6.283185307179586f : 6.283185307179586f) * invN;
    float sn, cs;
    __sincosf(base * (float)j, &sn, &cs);
    f2 w1 = (f2){cs, sn};
    f2 w2 = cmul2(w1, w1);
    f2 w3 = cmul2(w2, w1);
    f2 w4 = cmul2(w2, w2);
    f2 w5 = cmul2(w4, w1);
    f2 w6 = cmul2(w4, w2);
    f2 w7 = cmul2(w4, w3);
    x[1] = cmul2(x[1], w1);
    x[2] = cmul2(x[2], w2);
    x[3] = cmul2(x[3], w3);
    x[4] = cmul2(x[4], w4);
    x[5] = cmul2(x[5], w5);
    x[6] = cmul2(x[6], w6);
    x[7] = cmul2(x[7], w7);
}

__global__ __launch_bounds__(256, 2) void k_fft(__bf16* __restrict__ vty,
                                                const float* __restrict__ gre, const float* __restrict__ gim,
                                                const float* __restrict__ mrb, const float* __restrict__ gwp1) {
    __shared__ f2 Zp[2176];
    int pid = blockIdx.x;
    int b = pid >> 10, e = pid & 1023;
    int h = e >> 6, dh = e & 63;
    int bh = b * 16 + h;
    size_t gbase = (size_t)bh * NFREQ;
    size_t mbase = (size_t)h * NFMAX;
    __bf16* row = vty + ((size_t)b << 22) + ((size_t)e << 12);
    int t = threadIdx.x;

#pragma unroll
    for (int cc = 0; cc < 2; ++cc) {
        int c = t + cc * 256;
        bf16_8 a = *(const bf16_8*)&row[c * 8];
#pragma unroll
        for (int q = 0; q < 4; ++q)
            Zp[PD(c * 4 + q)] = (f2){(float)a[2 * q], (float)a[2 * q + 1]};
    }
    __syncthreads();

    f2 x[8];
    // ---- fwd S1 (D=256): cross-wave exchange -> full barrier after ----
    {
#pragma unroll
        for (int r = 0; r < 8; ++r) x[r] = Zp[PD(r * 256 + t)];
        dft8v<1>(x);
        tw8<1>(x, t, 1.0f / 2048.0f);
#pragma unroll
        for (int r = 0; r < 8; ++r) Zp[PD(r * 256 + t)] = x[r];
    }
    __syncthreads();
    // ---- fwd S2 (D=32): exchange confined to 32-thread group after this ----
    {
        int g = t >> 5, j = t & 31, base = g * 256 + j;
#pragma unroll
        for (int r = 0; r < 8; ++r) x[r] = Zp[PD(base + r * 32)];
        dft8v<1>(x);
        tw8<1>(x, j, 1.0f / 256.0f);
#pragma unroll
        for (int r = 0; r < 8; ++r) Zp[PD(base + r * 32)] = x[r];
    }
    WFENCE();
    // ---- fwd S3 (D=4) ----
    {
        int g = t >> 2, j = t & 3, base = g * 32 + j;
#pragma unroll
        for (int r = 0; r < 8; ++r) x[r] = Zp[PD(base + r * 4)];
        dft8v<1>(x);
        tw8<1>(x, j, 1.0f / 32.0f);
#pragma unroll
        for (int r = 0; r < 8; ++r) Zp[PD(base + r * 4)] = x[r];
    }
    WFENCE();
    // ---- fwd S4 (D=1) ----
    {
        int base = t * 8;
#pragma unroll
        for (int q = 0; q < 4; ++q) { x[q] = Zp[PD(base + q)]; x[4 + q] = Zp[PD(base + 4 + q)]; }
        dft4v<1>(x);
        dft4v<1>(x + 4);
#pragma unroll
        for (int q = 0; q < 4; ++q) { Zp[PD(base + q)] = x[q]; Zp[PD(base + 4 + q)] = x[4 + q]; }
    }
    __syncthreads();   // untangle scatters bit-reversed across whole array

    {
        float sn0, cs0;
        __sincosf(-1.5339807878856412e-3f * (float)(1 + t), &sn0, &cs0);
        f2 wk = (f2){cs0, sn0};
        const f2 W256 = (f2){0.92387953251128675613f, -0.38268343236508977172f};
#pragma unroll
        for (int r = 0; r < 4; ++r) {
            int k = 1 + (r << 8) + t;
            int k2 = 2048 - k;
            int sA = PD(SR8(k)), sB = PD(SR8(k2));
            float cs = wk.x, sn = wk.y;
            f2 Za = Zp[sA], Zb = Zp[sB];
            float Er = 0.5f * (Za.x + Zb.x), Ei = 0.5f * (Za.y - Zb.y);
            float Dr = 0.5f * (Za.x - Zb.x), Di = 0.5f * (Za.y + Zb.y);
            float WDr = cs * Dr - sn * Di, WDi = cs * Di + sn * Dr;
            float Tr = -WDi, Ti = WDr;
            float Vkr = Er - Tr, Vki = Ei - Ti;
            float Vk2r = Er + Tr, Vk2i = -(Ei + Ti);
            float g1r = gre[gbase + k], g1i = gim[gbase + k], b1v = mrb[mbase + k];
            float Ykr = Vkr * g1r - Vki * g1i, Yki = Vkr * g1i + Vki * g1r;
            float m1 = sqrtf(Ykr * Ykr + Yki * Yki);
            float s1 = fmaxf(m1 + b1v, 0.f) / (m1 + 1e-6f);
            Ykr *= s1; Yki *= s1;
            float g2r = gre[gbase + k2], g2i = gim[gbase + k2], b2v = mrb[mbase + k2];
            float Yk2r = Vk2r * g2r - Vk2i * g2i, Yk2i = Vk2r * g2i + Vk2i * g2r;
            float m2 = sqrtf(Yk2r * Yk2r + Yk2i * Yk2i);
            float s2 = fmaxf(m2 + b2v, 0.f) / (m2 + 1e-6f);
            Yk2r *= s2; Yk2i *= s2;
            float Epr = 0.5f * (Ykr + Yk2r), Epi = 0.5f * (Yki - Yk2i);
            float Fr = 0.5f * (Ykr - Yk2r), Fi = 0.5f * (Yki + Yk2i);
            float CWFr = cs * Fr + sn * Fi;
            float CWFi = cs * Fi - sn * Fr;
            Zp[sA] = (f2){Epr - CWFi, Epi + CWFr};
            Zp[sB] = (f2){Epr + CWFi, -Epi + CWFr};
            wk = cmul2(wk, W256);
        }
    }
    if (t == 0) {
        f2 Z0 = Zp[PD(0)];
        float V0 = Z0.x + Z0.y, VN = Z0.x - Z0.y;
        float g0r = gre[gbase], g0i = gim[gbase], b0v = mrb[mbase];
        float y0r = V0 * g0r, y0i = V0 * g0i;
        float m0 = sqrtf(y0r * y0r + y0i * y0i);
        float Y0 = y0r * (fmaxf(m0 + b0v, 0.f) / (m0 + 1e-6f));
        float gNr = gre[gbase + 2048], gNi = gim[gbase + 2048], bNv = mrb[mbase + 2048];
        float yNr = VN * gNr, yNi = VN * gNi;
        float mN = sqrtf(yNr * yNr + yNi * yNi);
        float YN = yNr * (fmaxf(mN + bNv, 0.f) / (mN + 1e-6f));
        Zp[PD(0)] = (f2){0.5f * (Y0 + YN), 0.5f * (Y0 - YN)};
    }
    __syncthreads();

    // ---- inv D=1 ----
    {
        int base = t * 8;
#pragma unroll
        for (int q = 0; q < 4; ++q) { x[q] = Zp[PD(base + q)]; x[4 + q] = Zp[PD(base + 4 + q)]; }
        dft4v<-1>(x);
        dft4v<-1>(x + 4);
#pragma unroll
        for (int q = 0; q < 4; ++q) { Zp[PD(base + q)] = x[q]; Zp[PD(base + 4 + q)] = x[4 + q]; }
    }
    WFENCE();
    // ---- inv D=4 ----
    {
        int g = t >> 2, j = t & 3, base = g * 32 + j;
#pragma unroll
        for (int r = 0; r < 8; ++r) x[r] = Zp[PD(base + r * 4)];
        tw8<-1>(x, j, 1.0f / 32.0f);
        dft8v<-1>(x);
#pragma unroll
        for (int r = 0; r < 8; ++r) Zp[PD(base + r * 4)] = x[r];
    }
    WFENCE();
    // ---- inv D=32 ----
    {
        int g = t >> 5, j = t & 31, base = g * 256 + j;
#pragma unroll
        for (int r = 0; r < 8; ++r) x[r] = Zp[PD(base + r * 32)];
        tw8<-1>(x, j, 1.0f / 256.0f);
        dft8v<-1>(x);
#pragma unroll
        for (int r = 0; r < 8; ++r) Zp[PD(base + r * 32)] = x[r];
    }
    __syncthreads();   // final stage gathers stride-256 across whole array
    // ---- inv D=256 + scale + pack + direct coalesced store ----
    {
#pragma unroll
        for (int r = 0; r < 8; ++r) x[r] = Zp[PD(r * 256 + t)];
        tw8<-1>(x, t, 1.0f / 2048.0f);
        dft8v<-1>(x);
        float sc = gwp1[bh * 64 + dh] * (1.0f / 2048.0f);
        unsigned int* row32 = (unsigned int*)row;
#pragma unroll
        for (int r = 0; r < 8; ++r) {
            __bf16 h1 = (__bf16)(x[r].x * sc);
            __bf16 h2 = (__bf16)(x[r].y * sc);
            unsigned int u = (unsigned int)__builtin_bit_cast(unsigned short, h1) |
                             ((unsigned int)__builtin_bit_cast(unsigned short, h2) << 16);
            row32[t + 256 * r] = u;
        }
    }
}

// ---------------- transpose: vt[b][e][l] bf16 -> ybf[b][l][e] bf16 ----------------
__global__ __launch_bounds__(256) void k_t2(const __bf16* __restrict__ vt, __bf16* __restrict__ ybf) {
    __shared__ __bf16 tl[64][66];
    int e0 = blockIdx.x * 64, l0 = blockIdx.y * 64, b = blockIdx.z;
    int t = threadIdx.x;
    const __bf16* src = vt + ((size_t)b << 22);
    __bf16* dst = ybf + ((size_t)b << 22);
    int er = t >> 3, lc = (t & 7) * 8;
#pragma unroll
    for (int it = 0; it < 2; ++it) {
        int e = er + it * 32;
        bf16_8 v = *(const bf16_8*)&src[(size_t)(e0 + e) * LSEQ + l0 + lc];
#pragma unroll
        for (int j = 0; j < 8; ++j) tl[e][lc + j] = v[j];
    }
    __syncthreads();
    int lr = t >> 3, ec = (t & 7) * 8;
#pragma unroll
    for (int it = 0; it < 2; ++it) {
        int l = lr + it * 32;
        bf16_8 v;
#pragma unroll
        for (int j = 0; j < 8; ++j) v[j] = tl[ec + j][l];
        *(bf16_8*)&dst[(size_t)(l0 + l) * DDIM + e0 + ec] = v;
    }
}

extern "C" void kernel_launch(void* const* d_in, const int* in_sizes, int n_in,
                              void* d_out, int out_size, void* d_ws, size_t ws_size,
                              hipStream_t stream) {
    const float* x      = (const float*)d_in[0];
    const float* Wq     = (const float*)d_in[1];
    const float* Wv     = (const float*)d_in[2];
    const float* Wo     = (const float*)d_in[3];
    const float* ln_g_s = (const float*)d_in[4];
    const float* ln_g_b = (const float*)d_in[5];
    const float* W1     = (const float*)d_in[6];
    const float* b1     = (const float*)d_in[7];
    const float* W2     = (const float*)d_in[8];
    const float* b2     = (const float*)d_in[9];
    const float* mrb    = (const float*)d_in[10];
    const float* ln_w_s = (const float*)d_in[11];
    const float* ln_w_b = (const float*)d_in[12];
    const float* Ww1    = (const float*)d_in[13];
    const float* bw1    = (const float*)d_in[14];
    const float* Ww2    = (const float*)d_in[15];
    const float* bw2    = (const float*)d_in[16];
    float* out = (float*)d_out;

    char* W = (char*)d_ws;
    __bf16* xbf = (__bf16*)W;                       // 33,554,432 B (later aliased as ybf)
    __bf16* ybf = xbf;
    __bf16* Wvb = (__bf16*)(W + 33554432);          // 2 MB
    __bf16* Wob = (__bf16*)(W + 35651584);          // 2 MB
    float*  xbp = (float*)(W + 37748736);
    float*  xbar= (float*)(W + 38010880);
    float*  qbar= (float*)(W + 38027264);
    float*  h1g = (float*)(W + 38043648);
    float*  gwp1= (float*)(W + 38109184);
    float*  gre = (float*)(W + 38125568);
    float*  gim = (float*)(W + 38650112);

    __bf16* vt = (__bf16*)d_out;                    // scratch inside d_out

    k_xbar_partial<<<dim3(4, 16, 4), 256, 0, stream>>>(x, xbp, xbf);
    k_cvt<<<1024, 256, 0, stream>>>(Wv, Wvb, DDIM * DDIM);
    k_cvt<<<1024, 256, 0, stream>>>(Wo, Wob, DDIM * DDIM);
    k_xbar_reduce<<<dim3(4, 4), 256, 0, stream>>>(xbp, xbar);
    k_qbar<<<256, 256, 0, stream>>>(xbar, Wq, qbar);
    k_mlp<<<64, 256, 0, stream>>>(qbar, ln_g_s, ln_g_b, W1, b1, ln_w_s, ln_w_b,
                                  Ww1, bw1, Ww2, bw2, h1g, gwp1);
    k_gate<<<1025, 256, 0, stream>>>(h1g, W2, b2, gre, gim);
    k_vgemm<<<256, 512, 0, stream>>>(xbf, Wvb, vt);
    k_fft<<<4096, 256, 0, stream>>>(vt, gre, gim, mrb, gwp1);
    k_t2<<<dim3(16, 64, 4), 256, 0, stream>>>(vt, ybf);
    k_ogemm<<<256, 512, 0, stream>>>(ybf, Wob, out);
}

// Round 19
// 193.755 us; speedup vs baseline: 1.0332x; 1.0332x over previous
//
#include <hip/hip_runtime.h>
#include <math.h>

#define LSEQ 4096
#define DDIM 1024
#define NB 4
#define NH 16
#define DHD 64
#define NFREQ 2049
#define NFMAX 4097

typedef __bf16 bf16_8 __attribute__((ext_vector_type(8)));
typedef float f32x4 __attribute__((ext_vector_type(4)));
typedef float f2 __attribute__((ext_vector_type(2)));

__device__ __forceinline__ float gelu_exact(float v) {
    return 0.5f * v * (1.0f + erff(v * 0.70710678118654752440f));
}

__device__ __forceinline__ void gload16(const void* g, void* l) {
    __builtin_amdgcn_global_load_lds((const __attribute__((address_space(1))) char*)g,
                                     (__attribute__((address_space(3))) char*)l, 16, 0, 0);
}

// ---------------- xbar partial + x -> bf16 cast (single pass over x) ----------------
__global__ __launch_bounds__(256) void k_xbar_partial(const float* __restrict__ x, float* __restrict__ xbp,
                                                      __bf16* __restrict__ xbf) {
    int d = blockIdx.x * 256 + threadIdx.x;
    int chunk = blockIdx.y;
    int b = blockIdx.z;
    size_t base = ((size_t)b * LSEQ + (size_t)chunk * 256) * DDIM + d;
    float acc = 0.f;
    for (int l = 0; l < 256; ++l) {
        float v = x[base + (size_t)l * DDIM];
        acc += v;
        xbf[base + (size_t)l * DDIM] = (__bf16)v;
    }
    xbp[(size_t)(b * 16 + chunk) * DDIM + d] = acc;
}

__global__ __launch_bounds__(256) void k_xbar_reduce(const float* __restrict__ xbp, float* __restrict__ xbar) {
    int d = blockIdx.x * 256 + threadIdx.x;
    int b = blockIdx.y;
    float acc = 0.f;
    for (int c = 0; c < 16; ++c) acc += xbp[(size_t)(b * 16 + c) * DDIM + d];
    xbar[b * DDIM + d] = acc * (1.0f / LSEQ);
}

// ---------------- weight fp32 -> bf16 ----------------
__global__ __launch_bounds__(256) void k_cvt(const float* __restrict__ s, __bf16* __restrict__ d, int n) {
    int i = (blockIdx.x * 256 + threadIdx.x) * 4;
    if (i < n) {
        float4 v = *(const float4*)(s + i);
        d[i] = (__bf16)v.x; d[i + 1] = (__bf16)v.y; d[i + 2] = (__bf16)v.z; d[i + 3] = (__bf16)v.w;
    }
}

// ---------------- q_bar = xbar @ Wq^T ----------------
__global__ __launch_bounds__(256) void k_qbar(const float* __restrict__ xbar, const float* __restrict__ Wq,
                                              float* __restrict__ qbar) {
    int lane = threadIdx.x & 63;
    int e = blockIdx.x * 4 + (threadIdx.x >> 6);
    const float* wrow = Wq + (size_t)e * DDIM;
    float a0 = 0, a1 = 0, a2 = 0, a3 = 0;
    for (int i = 0; i < 16; ++i) {
        int d = lane + i * 64;
        float w = wrow[d];
        a0 += w * xbar[d];
        a1 += w * xbar[DDIM + d];
        a2 += w * xbar[2 * DDIM + d];
        a3 += w * xbar[3 * DDIM + d];
    }
    for (int off = 32; off > 0; off >>= 1) {
        a0 += __shfl_down(a0, off);
        a1 += __shfl_down(a1, off);
        a2 += __shfl_down(a2, off);
        a3 += __shfl_down(a3, off);
    }
    if (lane == 0) {
        qbar[e] = a0;
        qbar[DDIM + e] = a1;
        qbar[2 * DDIM + e] = a2;
        qbar[3 * DDIM + e] = a3;
    }
}

// ---------------- per-(b,h) MLPs ----------------
__global__ __launch_bounds__(256) void k_mlp(const float* __restrict__ qbar,
                                             const float* __restrict__ ln_g_s, const float* __restrict__ ln_g_b,
                                             const float* __restrict__ W1, const float* __restrict__ b1,
                                             const float* __restrict__ ln_w_s, const float* __restrict__ ln_w_b,
                                             const float* __restrict__ Ww1, const float* __restrict__ bw1,
                                             const float* __restrict__ Ww2, const float* __restrict__ bw2,
                                             float* __restrict__ h1g, float* __restrict__ gwp1) {
    int bh = blockIdx.x;
    __shared__ float q[64], hg[64], hw[64], g1[64];
    __shared__ float sm, sv;
    int t = threadIdx.x;
    if (t < 64) q[t] = qbar[bh * 64 + t];
    __syncthreads();
    if (t == 0) {
        float m = 0;
        for (int i = 0; i < 64; ++i) m += q[i];
        m *= (1.0f / 64.0f);
        float v = 0;
        for (int i = 0; i < 64; ++i) { float dd = q[i] - m; v += dd * dd; }
        v *= (1.0f / 64.0f);
        sm = m; sv = v;
    }
    __syncthreads();
    if (t < 64) {
        float n = (q[t] - sm) * rsqrtf(sv + 1e-5f);
        hg[t] = n * ln_g_s[t] + ln_g_b[t];
        hw[t] = n * ln_w_s[t] + ln_w_b[t];
    }
    __syncthreads();
    {
        int f = t;
        const float* w = W1 + (size_t)f * 64;
        float s = b1[f];
        for (int d0 = 0; d0 < 64; ++d0) s += hg[d0] * w[d0];
        h1g[(size_t)bh * 256 + f] = gelu_exact(s);
    }
    if (t < 64) {
        const float* w = Ww1 + (size_t)t * 64;
        float s = bw1[t];
        for (int k = 0; k < 64; ++k) s += hw[k] * w[k];
        g1[t] = gelu_exact(s);
    }
    __syncthreads();
    if (t < 64) {
        const float* w = Ww2 + (size_t)t * 64;
        float s = bw2[t];
        for (int k = 0; k < 64; ++k) s += g1[k] * w[k];
        gwp1[bh * 64 + t] = 1.0f + 1.0f / (1.0f + expf(-s));
    }
}

// ---------------- gate rows ----------------
__global__ __launch_bounds__(256) void k_gate(const float* __restrict__ h1g, const float* __restrict__ W2,
                                              const float* __restrict__ b2,
                                              float* __restrict__ gre, float* __restrict__ gim) {
    int task = blockIdx.x * 4 + (threadIdx.x >> 6);
    if (task >= 2 * NFREQ) return;
    int lane = threadIdx.x & 63;
    int part = task >= NFREQ;
    int f = task - part * NFREQ;
    int row = part ? (NFMAX + f) : f;
    const float* w = W2 + (size_t)row * 256;
    float w0 = w[lane], w1 = w[64 + lane], w2 = w[128 + lane], w3 = w[192 + lane];
    float bias = b2[row];
    float* dst = part ? gim : gre;
    for (int bh = 0; bh < 64; ++bh) {
        const float* hr = h1g + (size_t)bh * 256;
        float p = w0 * hr[lane] + w1 * hr[64 + lane] + w2 * hr[128 + lane] + w3 * hr[192 + lane];
        for (int off = 32; off > 0; off >>= 1) p += __shfl_down(p, off);
        if (lane == 0) dst[(size_t)bh * NFREQ + f] = p + bias;
    }
}

// ================= 256x256, 8-wave, BK=64, dbuf LDS, counted-vmcnt pipeline (R12 best) =================
__device__ __forceinline__ void swz256(int bid, int& n0, int& m0, int& b) {
    int w = (bid & 7) * 32 + (bid >> 3);
    b = w >> 6;
    m0 = ((w >> 2) & 15) << 8;
    n0 = (w & 3) << 8;
}

__device__ __forceinline__ void g3_stage_half(const __bf16* __restrict__ src, int row0, int kt,
                                              char* ldshalf, int tid) {
#pragma unroll
    for (int j = 0; j < 2; ++j) {
        int c = j * 512 + tid;
        int r = c >> 3;
        int kc = ((c & 7) ^ (r & 7)) * 8;
        char* dst = ldshalf + (size_t)(j * 512 + (tid & ~63)) * 16;
        gload16(src + ((size_t)(row0 + r) << 10) + kt * 64 + kc, dst);
    }
}

__device__ __forceinline__ void g3_compute(const char* L, int db, int wm, int wn,
                                           int lrow, int lsl, f32x4 (&acc)[8][4]) {
    const char* Ab = L + db * 32768 + wm * 16384;
    const char* Bb = L + 65536 + db * 32768 + (wn >> 1) * 16384;
    int xs = lrow & 7;
    int brb = (wn & 1) * 64;
#pragma unroll
    for (int kk = 0; kk < 2; ++kk) {
        int slot = ((kk * 4 + lsl) ^ xs) << 4;
        bf16_8 af[8], bfr[4];
#pragma unroll
        for (int mi = 0; mi < 8; ++mi)
            af[mi] = *(const bf16_8*)(Ab + (mi * 16 + lrow) * 128 + slot);
#pragma unroll
        for (int ni = 0; ni < 4; ++ni)
            bfr[ni] = *(const bf16_8*)(Bb + (brb + ni * 16 + lrow) * 128 + slot);
        __builtin_amdgcn_s_setprio(1);
#pragma unroll
        for (int mi = 0; mi < 8; ++mi)
#pragma unroll
            for (int ni = 0; ni < 4; ++ni)
                acc[mi][ni] = __builtin_amdgcn_mfma_f32_16x16x32_bf16(af[mi], bfr[ni], acc[mi][ni], 0, 0, 0);
        __builtin_amdgcn_s_setprio(0);
    }
}

__device__ __forceinline__ void g3_core(const __bf16* __restrict__ A, const __bf16* __restrict__ B,
                                        int m0, int n0, char* L, f32x4 (&acc)[8][4]) {
    int tid = threadIdx.x;
    int lane = tid & 63, w = tid >> 6;
    int wm = w >> 2, wn = w & 3;
    int lrow = lane & 15, lsl = lane >> 4;
#pragma unroll
    for (int mi = 0; mi < 8; ++mi)
#pragma unroll
        for (int ni = 0; ni < 4; ++ni) acc[mi][ni] = (f32x4){0.f, 0.f, 0.f, 0.f};

#define G3_STAGE(KT, DB)                                                        \
    do {                                                                        \
        g3_stage_half(A, m0,       (KT), L + (DB) * 32768,               tid);  \
        g3_stage_half(A, m0 + 128, (KT), L + (DB) * 32768 + 16384,       tid);  \
        g3_stage_half(B, n0,       (KT), L + 65536 + (DB) * 32768,       tid);  \
        g3_stage_half(B, n0 + 128, (KT), L + 65536 + (DB) * 32768 + 16384, tid);\
    } while (0)

    G3_STAGE(0, 0);
    G3_STAGE(1, 1);
    asm volatile("s_waitcnt vmcnt(8)" ::: "memory");
    __builtin_amdgcn_s_barrier();
    asm volatile("" ::: "memory");
#pragma unroll 1
    for (int kt = 0; kt < 16; ++kt) {
        int db = kt & 1;
        g3_compute(L, db, wm, wn, lrow, lsl, acc);
        asm volatile("s_waitcnt lgkmcnt(0)" ::: "memory");
        __builtin_amdgcn_s_barrier();
        asm volatile("" ::: "memory");
        if (kt < 14) {
            G3_STAGE(kt + 2, db);
            asm volatile("s_waitcnt vmcnt(8)" ::: "memory");
            __builtin_amdgcn_s_barrier();
            asm volatile("" ::: "memory");
        } else if (kt == 14) {
            asm volatile("s_waitcnt vmcnt(0)" ::: "memory");
            __builtin_amdgcn_s_barrier();
            asm volatile("" ::: "memory");
        }
    }
#undef G3_STAGE
}

// vgemm: vt[b][e][l] (bf16) = (x @ Wv^T)^T
__global__ __launch_bounds__(512, 2) void k_vgemm(const __bf16* __restrict__ xbf, const __bf16* __restrict__ Wvb,
                                                  __bf16* __restrict__ vt) {
    __shared__ __align__(16) char L[131072 + 17408];
    __bf16 (*st)[16][68] = (__bf16(*)[16][68])(L + 131072);
    int n0, m0, b;
    swz256(blockIdx.x, n0, m0, b);
    f32x4 acc[8][4];
    g3_core(xbf + ((size_t)b << 22), Wvb, m0, n0, L, acc);
    int tid = threadIdx.x;
    int lane = tid & 63, w = tid >> 6;
    int wm = w >> 2, wn = w & 3;
    size_t vbase = ((size_t)b << 22);
#pragma unroll
    for (int ni = 0; ni < 4; ++ni) {
#pragma unroll
        for (int half = 0; half < 2; ++half) {
#pragma unroll
            for (int ml = 0; ml < 4; ++ml)
#pragma unroll
                for (int r = 0; r < 4; ++r)
                    st[w][lane & 15][ml * 16 + (lane >> 4) * 4 + r] = (__bf16)acc[half * 4 + ml][ni][r];
            asm volatile("" ::: "memory");
#pragma unroll
            for (int er = 0; er < 16; ++er) {
                vt[vbase + (size_t)(n0 + wn * 64 + ni * 16 + er) * LSEQ + m0 + wm * 128 + half * 64 + lane] =
                    st[w][er][lane];
            }
            asm volatile("" ::: "memory");
        }
    }
}

// ogemm: out[b][l][e2] (fp32) = ybf @ Wo^T
__global__ __launch_bounds__(512, 2) void k_ogemm(const __bf16* __restrict__ ybf, const __bf16* __restrict__ Wob,
                                                  float* __restrict__ out) {
    __shared__ __align__(16) char L[131072];
    int n0, m0, b;
    swz256(blockIdx.x, n0, m0, b);
    f32x4 acc[8][4];
    g3_core(ybf + ((size_t)b << 22), Wob, m0, n0, L, acc);
    int tid = threadIdx.x;
    int lane = tid & 63, w = tid >> 6;
    int wm = w >> 2, wn = w & 3;
    float* ob = out + ((size_t)b << 22);
#pragma unroll
    for (int mi = 0; mi < 8; ++mi)
#pragma unroll
        for (int ni = 0; ni < 4; ++ni)
#pragma unroll
            for (int r = 0; r < 4; ++r)
                ob[(size_t)(m0 + wm * 128 + mi * 16 + (lane >> 4) * 4 + r) * DDIM +
                   n0 + wn * 64 + ni * 16 + (lane & 15)] = acc[mi][ni][r];
}

// ================= rfft4096 per channel via cfft2048 (even/odd pack), radix 8-8-8-4 =================
// 8B-element pad PB(i) = i + 2*(i>>4): 16B inserted every 16 f2 -> (a) uniform 4 lanes per
// bank-pair for strides {256, 32, 4} (enumerated); (b) aligned 8-runs stay contiguous and
// 16B-aligned -> S4/invD1 LDS ops vectorize to b128.
__device__ __forceinline__ f2 cmul2(f2 a, f2 b) {
    f2 t = a * (f2){b.x, b.x};
    f2 ayx = __builtin_shufflevector(a, a, 1, 0);
    return t + ayx * (f2){-b.y, b.y};
}
__device__ __forceinline__ f2 mulmi(f2 v) {
    f2 s = __builtin_shufflevector(v, v, 1, 0);
    return s * (f2){1.f, -1.f};
}
__device__ __forceinline__ f2 mulpi(f2 v) {
    f2 s = __builtin_shufflevector(v, v, 1, 0);
    return s * (f2){-1.f, 1.f};
}
__device__ __forceinline__ int PB(int i) { return i + ((i >> 4) << 1); }
__device__ __forceinline__ int SR8(int k) {
    return ((k & 7) << 8) | (((k >> 3) & 7) << 5) | (((k >> 6) & 7) << 2) | (k >> 9);
}

#define WFENCE() asm volatile("s_waitcnt lgkmcnt(0)" ::: "memory")

template <int S>
__device__ __forceinline__ void dft4v(f2* x) {
    f2 t0 = x[0] + x[2], t1 = x[0] - x[2];
    f2 t2 = x[1] + x[3], t3 = x[1] - x[3];
    f2 j3 = (S == 1) ? mulmi(t3) : mulpi(t3);
    x[0] = t0 + t2;
    x[2] = t0 - t2;
    x[1] = t1 + j3;
    x[3] = t1 - j3;
}

template <int S>
__device__ __forceinline__ void dft8v(f2* x) {
    f2 e[4] = {x[0], x[2], x[4], x[6]};
    f2 o[4] = {x[1], x[3], x[5], x[7]};
    dft4v<S>(e);
    dft4v<S>(o);
    const float c = 0.7071067811865476f;
    const float sg = (S == 1) ? -1.f : 1.f;
    o[1] = cmul2(o[1], (f2){c, sg * c});
    o[2] = (S == 1) ? mulmi(o[2]) : mulpi(o[2]);
    o[3] = cmul2(o[3], (f2){-c, sg * c});
    x[0] = e[0] + o[0];
    x[4] = e[0] - o[0];
    x[1] = e[1] + o[1];
    x[5] = e[1] - o[1];
    x[2] = e[2] + o[2];
    x[6] = e[2] - o[2];
    x[3] = e[3] + o[3];
    x[7] = e[3] - o[3];
}

template <int S>
__device__ __forceinline__ void tw8(f2* x, int j, float invN) {
    float base = ((S == 1) ? -6.283185307179586f : 6.283185307179586f) * invN;
    float sn, cs;
    __sincosf(base * (float)j, &sn, &cs);
    f2 w1 = (f2){cs, sn};
    f2 w2 = cmul2(w1, w1);
    f2 w3 = cmul2(w2, w1);
    f2 w4 = cmul2(w2, w2);
    f2 w5 = cmul2(w4, w1);
    f2 w6 = cmul2(w4, w2);
    f2 w7 = cmul2(w4, w3);
    x[1] = cmul2(x[1], w1);
    x[2] = cmul2(x[2], w2);
    x[3] = cmul2(x[3], w3);
    x[4] = cmul2(x[4], w4);
    x[5] = cmul2(x[5], w5);
    x[6] = cmul2(x[6], w6);
    x[7] = cmul2(x[7], w7);
}

__global__ __launch_bounds__(256, 2) void k_fft(__bf16* __restrict__ vty,
                                                const float* __restrict__ gre, const float* __restrict__ gim,
                                                const float* __restrict__ mrb, const float* __restrict__ gwp1) {
    __shared__ __align__(16) f2 Zp[2304];
    int pid = blockIdx.x;
    int b = pid >> 10, e = pid & 1023;
    int h = e >> 6, dh = e & 63;
    int bh = b * 16 + h;
    size_t gbase = (size_t)bh * NFREQ;
    size_t mbase = (size_t)h * NFMAX;
    __bf16* row = vty + ((size_t)b << 22) + ((size_t)e << 12);
    int t = threadIdx.x;

    // ---- load: runs of 4 from base c*4 stay contiguous & 16B-aligned under PB ----
#pragma unroll
    for (int cc = 0; cc < 2; ++cc) {
        int c = t + cc * 256;
        bf16_8 a = *(const bf16_8*)&row[c * 8];
        float4* dst = (float4*)&Zp[PB(c * 4)];
        dst[0] = make_float4((float)a[0], (float)a[1], (float)a[2], (float)a[3]);
        dst[1] = make_float4((float)a[4], (float)a[5], (float)a[6], (float)a[7]);
    }
    __syncthreads();

    f2 x[8];
    // ---- fwd S1 (D=256): cross-wave -> full barrier ----
    {
#pragma unroll
        for (int r = 0; r < 8; ++r) x[r] = Zp[PB(r * 256 + t)];
        dft8v<1>(x);
        tw8<1>(x, t, 1.0f / 2048.0f);
#pragma unroll
        for (int r = 0; r < 8; ++r) Zp[PB(r * 256 + t)] = x[r];
    }
    __syncthreads();
    // ---- fwd S2 (D=32): exchange confined to 32-thread group after this ----
    {
        int g = t >> 5, j = t & 31, base = g * 256 + j;
#pragma unroll
        for (int r = 0; r < 8; ++r) x[r] = Zp[PB(base + r * 32)];
        dft8v<1>(x);
        tw8<1>(x, j, 1.0f / 256.0f);
#pragma unroll
        for (int r = 0; r < 8; ++r) Zp[PB(base + r * 32)] = x[r];
    }
    WFENCE();
    // ---- fwd S3 (D=4) ----
    {
        int g = t >> 2, j = t & 3, base = g * 32 + j;
#pragma unroll
        for (int r = 0; r < 8; ++r) x[r] = Zp[PB(base + r * 4)];
        dft8v<1>(x);
        tw8<1>(x, j, 1.0f / 32.0f);
#pragma unroll
        for (int r = 0; r < 8; ++r) Zp[PB(base + r * 4)] = x[r];
    }
    WFENCE();
    // ---- fwd S4 (D=1): contiguous aligned 8-run -> b128 LDS ops ----
    {
        int base = t * 8;
        float4* pp = (float4*)&Zp[PB(base)];
        float4 v0 = pp[0], v1 = pp[1], v2 = pp[2], v3 = pp[3];
        x[0] = (f2){v0.x, v0.y}; x[1] = (f2){v0.z, v0.w};
        x[2] = (f2){v1.x, v1.y}; x[3] = (f2){v1.z, v1.w};
        x[4] = (f2){v2.x, v2.y}; x[5] = (f2){v2.z, v2.w};
        x[6] = (f2){v3.x, v3.y}; x[7] = (f2){v3.z, v3.w};
        dft4v<1>(x);
        dft4v<1>(x + 4);
        pp[0] = make_float4(x[0].x, x[0].y, x[1].x, x[1].y);
        pp[1] = make_float4(x[2].x, x[2].y, x[3].x, x[3].y);
        pp[2] = make_float4(x[4].x, x[4].y, x[5].x, x[5].y);
        pp[3] = make_float4(x[6].x, x[6].y, x[7].x, x[7].y);
    }
    __syncthreads();   // untangle scatters bit-reversed across whole array

    {
        float sn0, cs0;
        __sincosf(-1.5339807878856412e-3f * (float)(1 + t), &sn0, &cs0);
        f2 wk = (f2){cs0, sn0};
        const f2 W256 = (f2){0.92387953251128675613f, -0.38268343236508977172f};
#pragma unroll
        for (int r = 0; r < 4; ++r) {
            int k = 1 + (r << 8) + t;
            int k2 = 2048 - k;
            int sA = PB(SR8(k)), sB = PB(SR8(k2));
            float cs = wk.x, sn = wk.y;
            f2 Za = Zp[sA], Zb = Zp[sB];
            float Er = 0.5f * (Za.x + Zb.x), Ei = 0.5f * (Za.y - Zb.y);
            float Dr = 0.5f * (Za.x - Zb.x), Di = 0.5f * (Za.y + Zb.y);
            float WDr = cs * Dr - sn * Di, WDi = cs * Di + sn * Dr;
            float Tr = -WDi, Ti = WDr;
            float Vkr = Er - Tr, Vki = Ei - Ti;
            float Vk2r = Er + Tr, Vk2i = -(Ei + Ti);
            float g1r = gre[gbase + k], g1i = gim[gbase + k], b1v = mrb[mbase + k];
            float Ykr = Vkr * g1r - Vki * g1i, Yki = Vkr * g1i + Vki * g1r;
            float m1 = sqrtf(Ykr * Ykr + Yki * Yki);
            float s1 = fmaxf(m1 + b1v, 0.f) / (m1 + 1e-6f);
            Ykr *= s1; Yki *= s1;
            float g2r = gre[gbase + k2], g2i = gim[gbase + k2], b2v = mrb[mbase + k2];
            float Yk2r = Vk2r * g2r - Vk2i * g2i, Yk2i = Vk2r * g2i + Vk2i * g2r;
            float m2 = sqrtf(Yk2r * Yk2r + Yk2i * Yk2i);
            float s2 = fmaxf(m2 + b2v, 0.f) / (m2 + 1e-6f);
            Yk2r *= s2; Yk2i *= s2;
            float Epr = 0.5f * (Ykr + Yk2r), Epi = 0.5f * (Yki - Yk2i);
            float Fr = 0.5f * (Ykr - Yk2r), Fi = 0.5f * (Yki + Yk2i);
            float CWFr = cs * Fr + sn * Fi;
            float CWFi = cs * Fi - sn * Fr;
            Zp[sA] = (f2){Epr - CWFi, Epi + CWFr};
            Zp[sB] = (f2){Epr + CWFi, -Epi + CWFr};
            wk = cmul2(wk, W256);
        }
    }
    if (t == 0) {
        f2 Z0 = Zp[PB(0)];
        float V0 = Z0.x + Z0.y, VN = Z0.x - Z0.y;
        float g0r = gre[gbase], g0i = gim[gbase], b0v = mrb[mbase];
        float y0r = V0 * g0r, y0i = V0 * g0i;
        float m0 = sqrtf(y0r * y0r + y0i * y0i);
        float Y0 = y0r * (fmaxf(m0 + b0v, 0.f) / (m0 + 1e-6f));
        float gNr = gre[gbase + 2048], gNi = gim[gbase + 2048], bNv = mrb[mbase + 2048];
        float yNr = VN * gNr, yNi = VN * gNi;
        float mN = sqrtf(yNr * yNr + yNi * yNi);
        float YN = yNr * (fmaxf(mN + bNv, 0.f) / (mN + 1e-6f));
        Zp[PB(0)] = (f2){0.5f * (Y0 + YN), 0.5f * (Y0 - YN)};
    }
    __syncthreads();

    // ---- inv D=1: b128 LDS ops ----
    {
        int base = t * 8;
        float4* pp = (float4*)&Zp[PB(base)];
        float4 v0 = pp[0], v1 = pp[1], v2 = pp[2], v3 = pp[3];
        x[0] = (f2){v0.x, v0.y}; x[1] = (f2){v0.z, v0.w};
        x[2] = (f2){v1.x, v1.y}; x[3] = (f2){v1.z, v1.w};
        x[4] = (f2){v2.x, v2.y}; x[5] = (f2){v2.z, v2.w};
        x[6] = (f2){v3.x, v3.y}; x[7] = (f2){v3.z, v3.w};
        dft4v<-1>(x);
        dft4v<-1>(x + 4);
        pp[0] = make_float4(x[0].x, x[0].y, x[1].x, x[1].y);
        pp[1] = make_float4(x[2].x, x[2].y, x[3].x, x[3].y);
        pp[2] = make_float4(x[4].x, x[4].y, x[5].x, x[5].y);
        pp[3] = make_float4(x[6].x, x[6].y, x[7].x, x[7].y);
    }
    WFENCE();
    // ---- inv D=4 ----
    {
        int g = t >> 2, j = t & 3, base = g * 32 + j;
#pragma unroll
        for (int r = 0; r < 8; ++r) x[r] = Zp[PB(base + r * 4)];
        tw8<-1>(x, j, 1.0f / 32.0f);
        dft8v<-1>(x);
#pragma unroll
        for (int r = 0; r < 8; ++r) Zp[PB(base + r * 4)] = x[r];
    }
    WFENCE();
    // ---- inv D=32 ----
    {
        int g = t >> 5, j = t & 31, base = g * 256 + j;
#pragma unroll
        for (int r = 0; r < 8; ++r) x[r] = Zp[PB(base + r * 32)];
        tw8<-1>(x, j, 1.0f / 256.0f);
        dft8v<-1>(x);
#pragma unroll
        for (int r = 0; r < 8; ++r) Zp[PB(base + r * 32)] = x[r];
    }
    __syncthreads();   // final stage gathers stride-256 across whole array
    // ---- inv D=256 + scale + pack + direct coalesced store ----
    {
#pragma unroll
        for (int r = 0; r < 8; ++r) x[r] = Zp[PB(r * 256 + t)];
        tw8<-1>(x, t, 1.0f / 2048.0f);
        dft8v<-1>(x);
        float sc = gwp1[bh * 64 + dh] * (1.0f / 2048.0f);
        unsigned int* row32 = (unsigned int*)row;
#pragma unroll
        for (int r = 0; r < 8; ++r) {
            __bf16 h1 = (__bf16)(x[r].x * sc);
            __bf16 h2 = (__bf16)(x[r].y * sc);
            unsigned int u = (unsigned int)__builtin_bit_cast(unsigned short, h1) |
                             ((unsigned int)__builtin_bit_cast(unsigned short, h2) << 16);
            row32[t + 256 * r] = u;
        }
    }
}

// ---------------- transpose: vt[b][e][l] bf16 -> ybf[b][l][e] bf16 ----------------
__global__ __launch_bounds__(256) void k_t2(const __bf16* __restrict__ vt, __bf16* __restrict__ ybf) {
    __shared__ __bf16 tl[64][66];
    int e0 = blockIdx.x * 64, l0 = blockIdx.y * 64, b = blockIdx.z;
    int t = threadIdx.x;
    const __bf16* src = vt + ((size_t)b << 22);
    __bf16* dst = ybf + ((size_t)b << 22);
    int er = t >> 3, lc = (t & 7) * 8;
#pragma unroll
    for (int it = 0; it < 2; ++it) {
        int e = er + it * 32;
        bf16_8 v = *(const bf16_8*)&src[(size_t)(e0 + e) * LSEQ + l0 + lc];
#pragma unroll
        for (int j = 0; j < 8; ++j) tl[e][lc + j] = v[j];
    }
    __syncthreads();
    int lr = t >> 3, ec = (t & 7) * 8;
#pragma unroll
    for (int it = 0; it < 2; ++it) {
        int l = lr + it * 32;
        bf16_8 v;
#pragma unroll
        for (int j = 0; j < 8; ++j) v[j] = tl[ec + j][l];
        *(bf16_8*)&dst[(size_t)(l0 + l) * DDIM + e0 + ec] = v;
    }
}

extern "C" void kernel_launch(void* const* d_in, const int* in_sizes, int n_in,
                              void* d_out, int out_size, void* d_ws, size_t ws_size,
                              hipStream_t stream) {
    const float* x      = (const float*)d_in[0];
    const float* Wq     = (const float*)d_in[1];
    const float* Wv     = (const float*)d_in[2];
    const float* Wo     = (const float*)d_in[3];
    const float* ln_g_s = (const float*)d_in[4];
    const float* ln_g_b = (const float*)d_in[5];
    const float* W1     = (const float*)d_in[6];
    const float* b1     = (const float*)d_in[7];
    const float* W2     = (const float*)d_in[8];
    const float* b2     = (const float*)d_in[9];
    const float* mrb    = (const float*)d_in[10];
    const float* ln_w_s = (const float*)d_in[11];
    const float* ln_w_b = (const float*)d_in[12];
    const float* Ww1    = (const float*)d_in[13];
    const float* bw1    = (const float*)d_in[14];
    const float* Ww2    = (const float*)d_in[15];
    const float* bw2    = (const float*)d_in[16];
    float* out = (float*)d_out;

    char* W = (char*)d_ws;
    __bf16* xbf = (__bf16*)W;                       // 33,554,432 B (later aliased as ybf)
    __bf16* ybf = xbf;
    __bf16* Wvb = (__bf16*)(W + 33554432);          // 2 MB
    __bf16* Wob = (__bf16*)(W + 35651584);          // 2 MB
    float*  xbp = (float*)(W + 37748736);
    float*  xbar= (float*)(W + 38010880);
    float*  qbar= (float*)(W + 38027264);
    float*  h1g = (float*)(W + 38043648);
    float*  gwp1= (float*)(W + 38109184);
    float*  gre = (float*)(W + 38125568);
    float*  gim = (float*)(W + 38650112);

    __bf16* vt = (__bf16*)d_out;                    // scratch inside d_out

    k_xbar_partial<<<dim3(4, 16, 4), 256, 0, stream>>>(x, xbp, xbf);
    k_cvt<<<1024, 256, 0, stream>>>(Wv, Wvb, DDIM * DDIM);
    k_cvt<<<1024, 256, 0, stream>>>(Wo, Wob, DDIM * DDIM);
    k_xbar_reduce<<<dim3(4, 4), 256, 0, stream>>>(xbp, xbar);
    k_qbar<<<256, 256, 0, stream>>>(xbar, Wq, qbar);
    k_mlp<<<64, 256, 0, stream>>>(qbar, ln_g_s, ln_g_b, W1, b1, ln_w_s, ln_w_b,
                                  Ww1, bw1, Ww2, bw2, h1g, gwp1);
    k_gate<<<1025, 256, 0, stream>>>(h1g, W2, b2, gre, gim);
    k_vgemm<<<256, 512, 0, stream>>>(xbf, Wvb, vt);
    k_fft<<<4096, 256, 0, stream>>>(vt, gre, gim, mrb, gwp1);
    k_t2<<<dim3(16, 64, 4), 256, 0, stream>>>(vt, ybf);
    k_ogemm<<<256, 512, 0, stream>>>(ybf, Wob, out);
}